// Round 1
// 406.457 us; speedup vs baseline: 1.0315x; 1.0315x over previous
//
#include <hip/hip_runtime.h>
#include <math.h>

typedef unsigned int uint32;
typedef __attribute__((ext_vector_type(8))) short bf16x8;
typedef __attribute__((ext_vector_type(4))) float f32x4;

__device__ __forceinline__ ushort f2bf(float f) {
  uint32 u = __builtin_bit_cast(uint32, f);
  uint32 r = (u + 0x7fff + ((u >> 16) & 1)) >> 16;  // RNE
  return (ushort)r;
}
__device__ __forceinline__ float bf_lo(uint32 u) {
  return __builtin_bit_cast(float, u << 16);
}
__device__ __forceinline__ float bf_hi(uint32 u) {
  return __builtin_bit_cast(float, u & 0xffff0000u);
}

// ---------------------------------------------------------------------------
// C[M,64] = A[M,K] @ W[64,K]^T via mfma_f32_16x16x32_bf16.
// Block: 256 thr (4 waves), tile 128 rows x 64 cols. W staged to LDS once
// (bf16, row stride 264), A staged per 32-k step (bf16, row stride 40).
// Wave w: rows w*32..w*32+31 (2 m-tiles), 4 n-tiles, 8 acc frags.
// Frag layouts (guide-verified): A[m=lane&15][k=quad*8+j]; B^T rows same;
// C/D: col=lane&15, row=quad*4+reg.
// ---------------------------------------------------------------------------
template <bool BF16OUT>
__global__ __launch_bounds__(256) void gemm_mfma(const float* __restrict__ A,
                                                 const float* __restrict__ W,
                                                 float* __restrict__ C,
                                                 ushort* __restrict__ Cb,
                                                 int M, int K) {
  __shared__ __align__(16) ushort Ws[64 * 264];
  __shared__ __align__(16) ushort As[128 * 40];
  const int t = threadIdx.x;
  const int lane = t & 63;
  const int w = t >> 6;
  const int quad = lane >> 4;
  const int l16 = lane & 15;
  const int rBase = blockIdx.x * 128;

  // stage W[64][K] -> bf16 LDS (coalesced float4 reads)
  const int kq4 = K >> 2;
  for (int idx = t; idx < 64 * kq4; idx += 256) {
    int row = idx / kq4, kq = idx - row * kq4;
    float4 v = *(const float4*)(W + (size_t)row * K + kq * 4);
    ushort4 b;
    b.x = f2bf(v.x); b.y = f2bf(v.y); b.z = f2bf(v.z); b.w = f2bf(v.w);
    *(ushort4*)&Ws[row * 264 + kq * 4] = b;
  }

  f32x4 acc[2][4];
  #pragma unroll
  for (int i = 0; i < 2; ++i)
    #pragma unroll
    for (int n = 0; n < 4; ++n) acc[i][n] = (f32x4){0.f, 0.f, 0.f, 0.f};

  const int rStage = t >> 1;      // 0..127
  const int halfStage = t & 1;    // 0..1

  for (int kb = 0; kb < K; kb += 32) {
    // stage A rows rBase..rBase+127, k in [kb, kb+32)
    {
      int gr = rBase + rStage;
      #pragma unroll
      for (int q = 0; q < 4; ++q) {
        int kk = kb + halfStage * 16 + q * 4;
        float4 v = make_float4(0.f, 0.f, 0.f, 0.f);
        if (gr < M) v = *(const float4*)(A + (size_t)gr * K + kk);
        ushort4 b;
        b.x = f2bf(v.x); b.y = f2bf(v.y); b.z = f2bf(v.z); b.w = f2bf(v.w);
        *(ushort4*)&As[rStage * 40 + halfStage * 16 + q * 4] = b;
      }
    }
    __syncthreads();

    bf16x8 afrag[2], bfrag[4];
    #pragma unroll
    for (int i = 0; i < 2; ++i)
      afrag[i] = *(const bf16x8*)&As[(w * 32 + i * 16 + l16) * 40 + quad * 8];
    #pragma unroll
    for (int n = 0; n < 4; ++n)
      bfrag[n] = *(const bf16x8*)&Ws[(n * 16 + l16) * 264 + kb + quad * 8];

    #pragma unroll
    for (int i = 0; i < 2; ++i)
      #pragma unroll
      for (int n = 0; n < 4; ++n)
        acc[i][n] = __builtin_amdgcn_mfma_f32_16x16x32_bf16(afrag[i], bfrag[n],
                                                            acc[i][n], 0, 0, 0);
    __syncthreads();
  }

  // epilogue: col = nt*16 + l16, row = w*32 + i*16 + quad*4 + r
  #pragma unroll
  for (int i = 0; i < 2; ++i)
    #pragma unroll
    for (int nt = 0; nt < 4; ++nt)
      #pragma unroll
      for (int r = 0; r < 4; ++r) {
        int row = rBase + w * 32 + i * 16 + quad * 4 + r;
        int col = nt * 16 + l16;
        if (row < M) {
          if (BF16OUT)
            Cb[(size_t)row * 64 + col] = f2bf(acc[i][nt][r]);
          else
            C[(size_t)row * 64 + col] = acc[i][nt][r];
        }
      }
}

// ---------------------------------------------------------------------------
// CSR build via two-level bucket sort (dense, full-line writes).
// ---------------------------------------------------------------------------
#define BBITS 7
#define BNODES 128
#define P_CHUNK 16384
#define P3_CAP 6144
#define MAXB 1024

__global__ __launch_bounds__(256) void bucket_count(const int* __restrict__ dst,
                                                    int* __restrict__ bucketCnt,
                                                    int E, int B) {
  __shared__ int lcnt[MAXB];
  const int t = threadIdx.x;
  for (int i = t; i < B; i += 256) lcnt[i] = 0;
  __syncthreads();
  int c0 = blockIdx.x * P_CHUNK, c1 = min(c0 + P_CHUNK, E);
  for (int i = c0 + t; i < c1; i += 256) atomicAdd(&lcnt[dst[i] >> BBITS], 1);
  __syncthreads();
  for (int b = t; b < B; b += 256) {
    int c = lcnt[b];
    if (c) atomicAdd(&bucketCnt[b], c);
  }
}

__global__ __launch_bounds__(1024) void bucket_scan(const int* __restrict__ bucketCnt,
                                                    int* __restrict__ bucketBase,
                                                    int* __restrict__ bucketCursor,
                                                    int* __restrict__ offsets,
                                                    int B, int N, int E) {
  __shared__ int waveSums[16];
  const int t = threadIdx.x;
  const int lane = t & 63, wave = t >> 6;
  int x = (t < B) ? bucketCnt[t] : 0;
  int inc = x;
  #pragma unroll
  for (int d = 1; d < 64; d <<= 1) {
    int o = __shfl_up(inc, d, 64);
    if (lane >= d) inc += o;
  }
  if (lane == 63) waveSums[wave] = inc;
  __syncthreads();
  int wbase = 0;
  #pragma unroll
  for (int w = 0; w < 16; ++w)
    if (w < wave) wbase += waveSums[w];
  int excl = wbase + inc - x;
  if (t < B) {
    bucketBase[t] = excl;
    bucketCursor[t] = excl;
  }
  if (t == 0) {
    bucketBase[B] = E;
    offsets[N] = E;
  }
}

__global__ __launch_bounds__(256) void bucket_partition(const int* __restrict__ src,
                                                        const int* __restrict__ dst,
                                                        int* __restrict__ bucketCursor,
                                                        unsigned* __restrict__ packed,
                                                        int E, int B) {
  __shared__ int lcnt[MAXB];
  __shared__ int lbase[MAXB];
  const int t = threadIdx.x;
  for (int i = t; i < B; i += 256) lcnt[i] = 0;
  __syncthreads();
  int c0 = blockIdx.x * P_CHUNK, c1 = min(c0 + P_CHUNK, E);
  for (int i = c0 + t; i < c1; i += 256) atomicAdd(&lcnt[dst[i] >> BBITS], 1);
  __syncthreads();
  for (int b = t; b < B; b += 256) {
    int c = lcnt[b];
    lbase[b] = c ? atomicAdd(&bucketCursor[b], c) : 0;
  }
  __syncthreads();
  for (int i = c0 + t; i < c1; i += 256) {
    int dv = dst[i];
    int b = dv >> BBITS;
    int pos = atomicAdd(&lbase[b], 1);
    packed[pos] = ((unsigned)src[i] << BBITS) | (unsigned)(dv & (BNODES - 1));
  }
}

__global__ __launch_bounds__(256) void bucket_finalize(const int* __restrict__ bucketBase,
                                                       unsigned* __restrict__ packed,
                                                       int* __restrict__ offsets, int N) {
  __shared__ unsigned stage[P3_CAP];
  __shared__ int cnt[BNODES];
  const int b = blockIdx.x;
  const int t = threadIdx.x;
  const int base = bucketBase[b];
  int n = bucketBase[b + 1] - base;
  if (n > P3_CAP) n = P3_CAP;
  for (int i = t; i < n; i += 256) stage[i] = packed[base + i];
  if (t < BNODES) cnt[t] = 0;
  __syncthreads();
  for (int i = t; i < n; i += 256) atomicAdd(&cnt[stage[i] & (BNODES - 1)], 1);
  __syncthreads();
  if (t < 64) {
    int cA = cnt[2 * t], cB = cnt[2 * t + 1];
    int s = cA + cB;
    int inc = s;
    #pragma unroll
    for (int d = 1; d < 64; d <<= 1) {
      int o = __shfl_up(inc, d, 64);
      if (t >= d) inc += o;
    }
    int excl = inc - s;
    cnt[2 * t] = base + excl;
    cnt[2 * t + 1] = base + excl + cA;
  }
  __syncthreads();
  const int node0 = b << BBITS;
  if (t < BNODES) {
    int g = node0 + t;
    if (g < N) offsets[g] = cnt[t];
  }
  __syncthreads();
  for (int i = t; i < n; i += 256) {
    unsigned v = stage[i];
    int pos = atomicAdd(&cnt[v & (BNODES - 1)], 1);
    packed[pos] = v >> BBITS;
  }
}

// ---------------------------------------------------------------------------
// One wave per dst, fused single-gather softmax aggregation.
// Quarter-wave (16 lanes x 4 dims) per edge, 4 edges per step, blocks of 32
// edges. z[src] rows gathered ONCE into registers (uint2/lane) and reused for
// both the logit dot and the weighted accumulation. df[d] register-resident
// (float4/lane). Cross-group combine via shfl_xor 16/32 at the end.
// ---------------------------------------------------------------------------
__global__ __launch_bounds__(256) void aggregate(const ushort* __restrict__ zb,
                                                 const float* __restrict__ df,
                                                 const int* __restrict__ offsets,
                                                 const int* __restrict__ edgeSrc,
                                                 float* __restrict__ out, int N) {
  int gwave = (blockIdx.x * blockDim.x + threadIdx.x) >> 6;
  int lane = threadIdx.x & 63;
  if (gwave >= N) return;
  const int d = __builtin_amdgcn_readfirstlane(gwave);
  const int g = lane >> 4;    // quarter-wave group: one edge per group per step
  const int l16 = lane & 15;  // 4 contiguous dims per lane
  const int beg = offsets[d];
  const int end = offsets[d + 1];

  // df row is wave-uniform; keep this lane's 4 dims (replicated across groups)
  const float4 df4 = *(const float4*)(df + (size_t)d * 64 + l16 * 4);

  float m = -INFINITY, l = 0.f;
  float ax = 0.f, ay = 0.f, az = 0.f, aw = 0.f;  // per-group partial acc

  for (int j0 = beg; j0 < end; j0 += 32) {
    const int nst = min(8, (end - j0 + 3) >> 2);  // steps of 4 edges
    uint2 zf[8];   // gathered z frags, statically indexed (unrolled)
    float ew[8];   // e, overwritten in place by w
    float bm = -INFINITY;

    // phase 1: coalesced gather + cooperative dot (16-lane tree reduce)
    #pragma unroll
    for (int st = 0; st < 8; ++st) {
      if (st < nst) {
        const int eidx = j0 + st * 4 + g;  // group-uniform
        const bool act = eidx < end;       // group-uniform predicate
        int s = 0;
        if (act) s = edgeSrc[eidx];
        zf[st] = *(const uint2*)(zb + (size_t)s * 64 + l16 * 4);
        float p = bf_lo(zf[st].x) * df4.x;
        p = fmaf(bf_hi(zf[st].x), df4.y, p);
        p = fmaf(bf_lo(zf[st].y), df4.z, p);
        p = fmaf(bf_hi(zf[st].y), df4.w, p);
        p += __shfl_xor(p, 1, 64);
        p += __shfl_xor(p, 2, 64);
        p += __shfl_xor(p, 4, 64);
        p += __shfl_xor(p, 8, 64);
        ew[st] = act ? p : -INFINITY;
        bm = fmaxf(bm, ew[st]);
      }
    }
    bm = fmaxf(bm, __shfl_xor(bm, 16, 64));
    bm = fmaxf(bm, __shfl_xor(bm, 32, 64));

    // online softmax update (nm/alpha wave-uniform)
    const float nm = fmaxf(m, bm);
    const float alpha = __expf(m - nm);
    float sw = 0.f;
    #pragma unroll
    for (int st = 0; st < 8; ++st) {
      if (st < nst) {
        const float w = __expf(ew[st] - nm);  // -INF -> 0 for padded slots
        ew[st] = w;
        sw += w;
      }
    }
    sw += __shfl_xor(sw, 16, 64);
    sw += __shfl_xor(sw, 32, 64);
    l = l * alpha + sw;
    m = nm;

    // phase 2: weighted accumulation from the SAME register frags
    ax *= alpha; ay *= alpha; az *= alpha; aw *= alpha;
    #pragma unroll
    for (int st = 0; st < 8; ++st) {
      if (st < nst) {
        const float w = ew[st];
        ax = fmaf(w, bf_lo(zf[st].x), ax);
        ay = fmaf(w, bf_hi(zf[st].x), ay);
        az = fmaf(w, bf_lo(zf[st].y), az);
        aw = fmaf(w, bf_hi(zf[st].y), aw);
      }
    }
  }

  // combine the 4 per-group partials
  ax += __shfl_xor(ax, 16, 64); ax += __shfl_xor(ax, 32, 64);
  ay += __shfl_xor(ay, 16, 64); ay += __shfl_xor(ay, 32, 64);
  az += __shfl_xor(az, 16, 64); az += __shfl_xor(az, 32, 64);
  aw += __shfl_xor(aw, 16, 64); aw += __shfl_xor(aw, 32, 64);

  if (lane < 16) {
    const float inv = (l > 0.f) ? (1.f / l) : 0.f;
    float4 o;
    o.x = ax * inv; o.y = ay * inv; o.z = az * inv; o.w = aw * inv;
    *(float4*)(out + (size_t)d * 64 + l16 * 4) = o;
  }
}

// ---------------------------------------------------------------------------
extern "C" void kernel_launch(void* const* d_in, const int* in_sizes, int n_in,
                              void* d_out, int out_size, void* d_ws, size_t ws_size,
                              hipStream_t stream) {
  const float* h     = (const float*)d_in[0];  // [N,256]
  const float* feat  = (const float*)d_in[1];  // [N,64]
  const float* W_fc  = (const float*)d_in[2];  // [64,256]
  const float* W_dst = (const float*)d_in[3];  // [64,64]
  const int*   src   = (const int*)d_in[4];    // [E]
  const int*   dst   = (const int*)d_in[5];    // [E]
  float* out = (float*)d_out;

  const int N = in_sizes[1] / 64;        // 100000
  const int E = in_sizes[4];             // 1600000
  const int IN_DIM = in_sizes[0] / N;    // 256
  const int FEAT_DIM = 64;
  const int B = (N + BNODES - 1) >> BBITS;  // 782

  // workspace layout
  char* ws = (char*)d_ws;
  ushort* zb = (ushort*)ws;                        // N*64 bf16
  float* df = (float*)(zb + (size_t)N * 64);       // N*64 f32
  int* offsets = (int*)(df + (size_t)N * 64);      // N+1
  unsigned* packed = (unsigned*)(offsets + N + 1); // E (becomes edgeSrc)
  int* bucketCnt = (int*)(packed + E);             // B
  int* bucketBase = bucketCnt + B;                 // B+1
  int* bucketCursor = bucketBase + B + 1;          // B

  hipMemsetAsync(bucketCnt, 0, sizeof(int) * (size_t)B, stream);

  int ggrid = (N + 127) / 128;  // 782
  gemm_mfma<true><<<ggrid, 256, 0, stream>>>(h, W_fc, nullptr, zb, N, IN_DIM);
  gemm_mfma<false><<<ggrid, 256, 0, stream>>>(feat, W_dst, df, nullptr, N, FEAT_DIM);

  int pgrid = (E + P_CHUNK - 1) / P_CHUNK;  // 98
  bucket_count<<<pgrid, 256, 0, stream>>>(dst, bucketCnt, E, B);
  bucket_scan<<<1, 1024, 0, stream>>>(bucketCnt, bucketBase, bucketCursor, offsets, B, N, E);
  bucket_partition<<<pgrid, 256, 0, stream>>>(src, dst, bucketCursor, packed, E, B);
  bucket_finalize<<<B, 256, 0, stream>>>(bucketBase, packed, offsets, N);

  aggregate<<<(N + 3) / 4, 256, 0, stream>>>(zb, df, offsets, (const int*)packed, out, N);
}